// Round 1
// baseline (205.820 us; speedup 1.0000x reference)
//
#include <hip/hip_runtime.h>

// Problem: N=65536 rows, C=100 classes, 6 matrices (outputs1..5, mimic).
// out[0]            = max over ALL elements of outputs1..5
// out[1 + row*6 + j]= softmax_j(margins(row)/TEMP), TEMP=2
// margin(x,t) = (x[t] == max(x)) ? max(x) - second_max(x) : 0
//
// R8 theory: R0-R7 scatter variants are request-path bound: thread-per-
// (half-row,matrix) puts adjacent lanes 192-208B apart, so every wave
// dwordx4 hits 64 distinct cache lines (~237 cyc/vmem instr measured).
// This version stages a 64-row x 400B tile per block into LDS via
// global_load_lds (16B/lane, wave-linear dest -> 16 lines/instr, fully
// coalesced), then computes top-2 from LDS with 4 threads/row.
// LDS 25.6KB -> 6 blocks/CU = 24 waves (75%). Predicted margin kernel
// 61 -> ~30us, supply-BW bound.

constexpr int C       = 100;
constexpr int ROWS    = 64;          // rows per LDS tile (64*100*4 = 25600 B)
constexpr float INV_TEMP = 0.5f;     // 1/TEMP

// Order-preserving float -> unsigned encoding for atomicMax.
// enc(f) >= enc(-inf) = 0x007FFFFF > 0, so memset-0 is a valid identity.
__device__ __forceinline__ unsigned enc_f(float f) {
    unsigned u = __float_as_uint(f);
    return (u & 0x80000000u) ? ~u : (u | 0x80000000u);
}

// Async global->LDS, 16B per lane. LDS dest is wave-uniform base (firstlane)
// + lane*16, which matches our linear per-thread layout exactly.
__device__ __forceinline__ void async_cp16(const float* g, float* l) {
    __builtin_amdgcn_global_load_lds(
        (const __attribute__((address_space(1))) void*)g,
        (__attribute__((address_space(3))) void*)l,
        16, 0, 0);
}

// Grid: (ceil(n/64), 6). Block: 256 threads. Block = (row-tile, matrix).
__global__ __launch_bounds__(256) void margin_kernel(
    const float* __restrict__ o1, const float* __restrict__ o2,
    const float* __restrict__ o3, const float* __restrict__ o4,
    const float* __restrict__ o5, const float* __restrict__ mimic,
    const int* __restrict__ tgt, float* __restrict__ out,
    unsigned* __restrict__ ws, int n)
{
    __shared__ float    tile[ROWS * C];   // 25600 B
    __shared__ unsigned wmax[4];

    const int m    = blockIdx.y;                       // 0..5 (uniform)
    const int tid  = threadIdx.x;
    const int lane = tid & 63;

    const float* __restrict__ mat =
        (m == 0) ? o1 : (m == 1) ? o2 : (m == 2) ? o3 :
        (m == 3) ? o4 : (m == 4) ? o5 : mimic;

    // int32-vs-int64 target layout detection (wave-uniform).
    // int64 little-endian nonneg => odd 32-bit words all zero.
    const int pidx  = 2 * lane + 1;
    const int probe = (pidx < n) ? tgt[pidx] : 0;
    const unsigned long long nz = __ballot(probe != 0);
    const int tstride = (nz == 0ull) ? 2 : 1;

    // ---- stage tile: ROWS*C = 6400 floats, fully coalesced 16B chunks ----
    // 6 rounds of 256 threads x 16B (24576 B) + one 64-thread round (1024 B).
    const size_t base   = (size_t)blockIdx.x * (ROWS * C);  // float index
    const size_t maxIdx = (size_t)n * C - 4;                // tail clamp (16B-aligned: C%4==0)
    #pragma unroll
    for (int c = 0; c < 6; ++c) {
        const int    off = (c * 256 + tid) * 4;
        const size_t g   = base + (size_t)off;
        async_cp16(mat + (g <= maxIdx ? g : maxIdx), tile + off);
    }
    if (tid < 64) {                       // wave-0-uniform branch
        const int    off = 6 * 1024 + tid * 4;   // floats 6144..6399
        const size_t g   = base + (size_t)off;
        async_cp16(mat + (g <= maxIdx ? g : maxIdx), tile + off);
    }
    __syncthreads();   // compiler drains vmcnt(0) before s_barrier

    // ---- top-2 per row: 4 threads/row, 25 floats each ----
    const int rl  = tid >> 2;             // local row 0..63
    const int q   = tid & 3;              // quarter 0..3
    const int row = blockIdx.x * ROWS + rl;

    const float* p = tile + rl * C + q * 25;
    // two interleaved trackers (even/odd) for fmax-chain ILP
    float a1 = -INFINITY, a2 = -INFINITY;
    float b1 = -INFINITY, b2 = -INFINITY;
    #pragma unroll
    for (int i = 0; i < 12; ++i) {
        const float va = p[2 * i], vb = p[2 * i + 1];
        a2 = fmaxf(a2, fminf(a1, va)); a1 = fmaxf(a1, va);
        b2 = fmaxf(b2, fminf(b1, vb)); b1 = fmaxf(b1, vb);
    }
    { const float v = p[24]; a2 = fmaxf(a2, fminf(a1, v)); a1 = fmaxf(a1, v); }
    float m1 = fmaxf(a1, b1);
    float m2 = fmaxf(fminf(a1, b1), fmaxf(a2, b2));

    // merge the 4 quarter-threads (lanes 4k..4k+3; quarters disjoint -> exact)
    #pragma unroll
    for (int s = 1; s <= 2; s <<= 1) {
        const float p1 = __shfl_xor(m1, s);
        const float p2 = __shfl_xor(m2, s);
        m2 = fmaxf(fminf(m1, p1), fmaxf(m2, p2));
        m1 = fmaxf(m1, p1);
    }

    if (q == 0 && row < n) {
        const int   t  = tgt[(size_t)row * tstride];   // 0..99
        const float tv = tile[rl * C + t];             // LDS hit
        out[1 + (size_t)row * 6 + m] = (tv == m1) ? (m1 - m2) * INV_TEMP : 0.0f;
    }

    // ---- global max over matrices 0..4: wave reduce, 4-slot LDS, 1 atomic ----
    float gm = (row < n) ? m1 : -INFINITY;
    #pragma unroll
    for (int s = 1; s < 64; s <<= 1) gm = fmaxf(gm, __shfl_xor(gm, s));
    if (m < 5) {                                  // block-uniform branch
        if (lane == 0) wmax[tid >> 6] = enc_f(gm);
        __syncthreads();
        if (tid == 0)
            atomicMax(ws, max(max(wmax[0], wmax[1]), max(wmax[2], wmax[3])));
    }
}

// In-place 6-wide softmax over out[1+row*6 .. +5]; thread 0 decodes out[0].
__global__ __launch_bounds__(256) void softmax_kernel(
    float* __restrict__ out, const unsigned* __restrict__ ws, int n)
{
    const int row = blockIdx.x * blockDim.x + threadIdx.x;
    if (row < n) {
        float* p = out + 1 + (size_t)row * 6;
        float mrg[6];
        #pragma unroll
        for (int j = 0; j < 6; ++j) mrg[j] = p[j];
        float mx = mrg[0];
        #pragma unroll
        for (int j = 1; j < 6; ++j) mx = fmaxf(mx, mrg[j]);
        float e[6], s = 0.0f;
        #pragma unroll
        for (int j = 0; j < 6; ++j) { e[j] = __expf(mrg[j] - mx); s += e[j]; }
        const float inv = 1.0f / s;
        #pragma unroll
        for (int j = 0; j < 6; ++j) p[j] = e[j] * inv;
    }
    if (row == 0) {
        const unsigned e = ws[0];
        const unsigned bits = (e & 0x80000000u) ? (e & 0x7FFFFFFFu) : ~e;
        out[0] = __uint_as_float(bits);
    }
}

extern "C" void kernel_launch(void* const* d_in, const int* in_sizes, int n_in,
                              void* d_out, int out_size, void* d_ws, size_t ws_size,
                              hipStream_t stream) {
    const float* o1    = (const float*)d_in[0];
    const float* o2    = (const float*)d_in[1];
    const float* o3    = (const float*)d_in[2];
    const float* o4    = (const float*)d_in[3];
    const float* o5    = (const float*)d_in[4];
    const float* mimic = (const float*)d_in[5];
    const int*   tgt   = (const int*)d_in[6];
    float*       out   = (float*)d_out;
    unsigned*    ws    = (unsigned*)d_ws;

    const int n = in_sizes[6];   // N = 65536

    // ws[0] = encoded running max; 0 is the identity for the encoding.
    hipMemsetAsync(ws, 0, sizeof(unsigned), stream);

    dim3 grid((n + ROWS - 1) / ROWS, 6);   // 1024 x 6 = 6144 blocks
    margin_kernel<<<grid, 256, 0, stream>>>(o1, o2, o3, o4, o5, mimic,
                                            tgt, out, ws, n);
    softmax_kernel<<<(n + 255) / 256, 256, 0, stream>>>(out, ws, n);
}

// Round 2
// 202.335 us; speedup vs baseline: 1.0172x; 1.0172x over previous
//
#include <hip/hip_runtime.h>

// Problem: N=65536 rows, C=100 classes, 6 matrices (outputs1..5, mimic).
// out[0]            = max over ALL elements of outputs1..5
// out[1 + row*6 + j]= softmax_j(margins(row)/TEMP), TEMP=2
// margin(x,t) = (x[t] == max(x)) ? max(x) - second_max(x) : 0
//
// R9: R8 (LDS-staged coalesced) regressed 61.6->77us: barrier drains vmcnt(0),
// 6 blocks/CU serialize {load, latency, compute}. Winning regime = barrier-free
// full-occupancy scatter; remaining lever = per-instr line-requests.
// This version: wave-cooperative rows. 8 lanes/row, lane sub reads f4
// {sub, 8+sub, 16+sub} (+f4 24 on sub==0) -> 8-lane groups read 128B
// contiguous => ~22 lines/wave-instr vs 64 (3x fewer L1/L2 requests, zero
// refetch). Top-2 merged across 8 lanes via 3 shfl_xor; target value pulled
// from already-loaded regs (no scattered tv load). No LDS tile, no barrier,
// 2 rows/thread, 24576 waves = 96/CU demanded -> full residency.

constexpr int C = 100;
constexpr float INV_TEMP = 0.5f;   // 1/TEMP

// Order-preserving float -> unsigned encoding for atomicMax.
// enc(f) >= enc(-inf) = 0x007FFFFF > 0, so memset-0 is a valid identity.
__device__ __forceinline__ unsigned enc_f(float f) {
    unsigned u = __float_as_uint(f);
    return (u & 0x80000000u) ? ~u : (u | 0x80000000u);
}

__device__ __forceinline__ void t2(float& m1, float& m2, float v) {
    m2 = fmaxf(m2, fminf(m1, v));
    m1 = fmaxf(m1, v);
}

// Top-2 of this lane's 16-float slice (4 independent tracker chains for ILP).
__device__ __forceinline__ void row_top2(const float4 v0, const float4 v1,
                                         const float4 v2, const float4 v3,
                                         float& M1, float& M2) {
    float a1=-INFINITY,a2=-INFINITY,b1=-INFINITY,b2=-INFINITY;
    float c1=-INFINITY,c2=-INFINITY,d1=-INFINITY,d2=-INFINITY;
    t2(a1,a2,v0.x); t2(b1,b2,v0.y); t2(c1,c2,v0.z); t2(d1,d2,v0.w);
    t2(a1,a2,v1.x); t2(b1,b2,v1.y); t2(c1,c2,v1.z); t2(d1,d2,v1.w);
    t2(a1,a2,v2.x); t2(b1,b2,v2.y); t2(c1,c2,v2.z); t2(d1,d2,v2.w);
    t2(a1,a2,v3.x); t2(b1,b2,v3.y); t2(c1,c2,v3.z); t2(d1,d2,v3.w);
    const float ab1 = fmaxf(a1,b1), ab2 = fmaxf(fminf(a1,b1), fmaxf(a2,b2));
    const float cd1 = fmaxf(c1,d1), cd2 = fmaxf(fminf(c1,d1), fmaxf(c2,d2));
    M1 = fmaxf(ab1, cd1);
    M2 = fmaxf(fminf(ab1, cd1), fmaxf(ab2, cd2));
}

// Candidate target-value: the one lane owning element t returns it, others -inf.
// f4 layout per lane: v0=f4[sub], v1=f4[8+sub], v2=f4[16+sub], v3=f4[24] (sub 0).
__device__ __forceinline__ float tgt_cand(int t, int sub,
                                          const float4 v0, const float4 v1,
                                          const float4 v2, const float4 v3) {
    const int fidx  = t >> 2;                       // 0..24
    const int comp  = t & 3;
    const int owner = (fidx < 24) ? (fidx & 7) : 0;
    if (sub != owner) return -INFINITY;
    const int regi  = (fidx < 24) ? (fidx >> 3) : 3;
    const float4 v  = (regi == 0) ? v0 : (regi == 1) ? v1 : (regi == 2) ? v2 : v3;
    return (comp == 0) ? v.x : (comp == 1) ? v.y : (comp == 2) ? v.z : v.w;
}

// Grid: (ceil(n/64), 6). Block: 256 threads. 8 lanes/row, 2 rows/thread-slot.
__global__ __launch_bounds__(256) void margin_kernel(
    const float* __restrict__ o1, const float* __restrict__ o2,
    const float* __restrict__ o3, const float* __restrict__ o4,
    const float* __restrict__ o5, const float* __restrict__ mimic,
    const int* __restrict__ tgt, float* __restrict__ out,
    unsigned* __restrict__ ws, int n)
{
    __shared__ unsigned wmax[4];

    const int m    = blockIdx.y;             // 0..5 (uniform)
    const int tid  = threadIdx.x;
    const int lane = tid & 63;
    const int sub  = lane & 7;               // lane within row-group
    const int rg   = lane >> 3;              // row-group 0..7
    const int wv   = tid >> 6;               // wave 0..3

    const float* __restrict__ mat =
        (m == 0) ? o1 : (m == 1) ? o2 : (m == 2) ? o3 :
        (m == 3) ? o4 : (m == 4) ? o5 : mimic;

    // int32-vs-int64 target layout detection (wave-uniform).
    // int64 little-endian nonneg => odd 32-bit words all zero.
    const int pidx  = 2 * lane + 1;
    const int probe = (pidx < n) ? tgt[pidx] : 0;
    const unsigned long long nz = __ballot(probe != 0);
    const int tstride = (nz == 0ull) ? 2 : 1;

    // two rows per thread-slot; waves cover 16 consecutive rows each
    const int rowA0 = blockIdx.x * 64 + wv * 16 + rg;
    const int rowB0 = rowA0 + 8;
    const int rowA  = min(rowA0, n - 1);     // clamp for safe addressing
    const int rowB  = min(rowB0, n - 1);

    const float4* __restrict__ pA = (const float4*)(mat + (size_t)rowA * C);
    const float4* __restrict__ pB = (const float4*)(mat + (size_t)rowB * C);

    // issue all loads up front (independent -> deep vmcnt queue)
    const float4 vA0 = pA[sub], vA1 = pA[8 + sub], vA2 = pA[16 + sub];
    const float4 vB0 = pB[sub], vB1 = pB[8 + sub], vB2 = pB[16 + sub];
    float4 vA3 = make_float4(-INFINITY, -INFINITY, -INFINITY, -INFINITY);
    float4 vB3 = vA3;
    int tA = 0, tB = 0;
    if (sub == 0) {                          // tail f4 + target index
        vA3 = pA[24];
        vB3 = pB[24];
        tA  = tgt[(size_t)rowA * tstride];
        tB  = tgt[(size_t)rowB * tstride];
    }
    tA = __shfl(tA, lane & 56);              // broadcast within row-group
    tB = __shfl(tB, lane & 56);

    float m1A, m2A, m1B, m2B;
    row_top2(vA0, vA1, vA2, vA3, m1A, m2A);
    row_top2(vB0, vB1, vB2, vB3, m1B, m2B);
    float cA = tgt_cand(tA, sub, vA0, vA1, vA2, vA3);
    float cB = tgt_cand(tB, sub, vB0, vB1, vB2, vB3);

    // merge the 8 lanes of each row-group (disjoint slices -> exact)
    #pragma unroll
    for (int s = 1; s <= 4; s <<= 1) {
        const float o1A = __shfl_xor(m1A, s), o2A = __shfl_xor(m2A, s);
        const float ocA = __shfl_xor(cA, s);
        m2A = fmaxf(fminf(m1A, o1A), fmaxf(m2A, o2A));
        m1A = fmaxf(m1A, o1A);
        cA  = fmaxf(cA, ocA);
        const float o1B = __shfl_xor(m1B, s), o2B = __shfl_xor(m2B, s);
        const float ocB = __shfl_xor(cB, s);
        m2B = fmaxf(fminf(m1B, o1B), fmaxf(m2B, o2B));
        m1B = fmaxf(m1B, o1B);
        cB  = fmaxf(cB, ocB);
    }

    if (sub == 0) {
        if (rowA0 < n)
            out[1 + (size_t)rowA0 * 6 + m] = (cA == m1A) ? (m1A - m2A) * INV_TEMP : 0.0f;
        if (rowB0 < n)
            out[1 + (size_t)rowB0 * 6 + m] = (cB == m1B) ? (m1B - m2B) * INV_TEMP : 0.0f;
    }

    // global max over matrices 0..4: wave reduce, 4-slot LDS, 1 atomic/block
    float gm = fmaxf(rowA0 < n ? m1A : -INFINITY,
                     rowB0 < n ? m1B : -INFINITY);
    #pragma unroll
    for (int s = 1; s < 64; s <<= 1) gm = fmaxf(gm, __shfl_xor(gm, s));
    if (m < 5) {                             // block-uniform branch
        if (lane == 0) wmax[wv] = enc_f(gm);
        __syncthreads();
        if (tid == 0)
            atomicMax(ws, max(max(wmax[0], wmax[1]), max(wmax[2], wmax[3])));
    }
}

// In-place 6-wide softmax over out[1+row*6 .. +5]; thread 0 decodes out[0].
__global__ __launch_bounds__(256) void softmax_kernel(
    float* __restrict__ out, const unsigned* __restrict__ ws, int n)
{
    const int row = blockIdx.x * blockDim.x + threadIdx.x;
    if (row < n) {
        float* p = out + 1 + (size_t)row * 6;
        float mrg[6];
        #pragma unroll
        for (int j = 0; j < 6; ++j) mrg[j] = p[j];
        float mx = mrg[0];
        #pragma unroll
        for (int j = 1; j < 6; ++j) mx = fmaxf(mx, mrg[j]);
        float e[6], s = 0.0f;
        #pragma unroll
        for (int j = 0; j < 6; ++j) { e[j] = __expf(mrg[j] - mx); s += e[j]; }
        const float inv = 1.0f / s;
        #pragma unroll
        for (int j = 0; j < 6; ++j) p[j] = e[j] * inv;
    }
    if (row == 0) {
        const unsigned e = ws[0];
        const unsigned bits = (e & 0x80000000u) ? (e & 0x7FFFFFFFu) : ~e;
        out[0] = __uint_as_float(bits);
    }
}

extern "C" void kernel_launch(void* const* d_in, const int* in_sizes, int n_in,
                              void* d_out, int out_size, void* d_ws, size_t ws_size,
                              hipStream_t stream) {
    const float* o1    = (const float*)d_in[0];
    const float* o2    = (const float*)d_in[1];
    const float* o3    = (const float*)d_in[2];
    const float* o4    = (const float*)d_in[3];
    const float* o5    = (const float*)d_in[4];
    const float* mimic = (const float*)d_in[5];
    const int*   tgt   = (const int*)d_in[6];
    float*       out   = (float*)d_out;
    unsigned*    ws    = (unsigned*)d_ws;

    const int n = in_sizes[6];   // N = 65536

    // ws[0] = encoded running max; 0 is the identity for the encoding.
    hipMemsetAsync(ws, 0, sizeof(unsigned), stream);

    dim3 grid((n + 63) / 64, 6);   // 1024 x 6 = 6144 blocks, 24576 waves
    margin_kernel<<<grid, 256, 0, stream>>>(o1, o2, o3, o4, o5, mimic,
                                            tgt, out, ws, n);
    softmax_kernel<<<(n + 255) / 256, 256, 0, stream>>>(out, ws, n);
}